// Round 2
// baseline (141.252 us; speedup 1.0000x reference)
//
#include <hip/hip_runtime.h>
#include <hip/hip_bf16.h>

// Problem constants: B=4, N=4096, C=256, H=8 heads, G=4 groups, d=32, n=1024
// M_TOT = B*N = 16384 rows.

typedef __attribute__((ext_vector_type(8))) short bf16x8;  // 8 bf16 (4 VGPRs)
typedef __attribute__((ext_vector_type(4))) float f32x4;

__device__ __forceinline__ unsigned short f2bf(float x){
  __hip_bfloat16 h = __float2bfloat16(x);   // RNE; compiler can fuse pairs to v_cvt_pk_bf16_f32
  return __builtin_bit_cast(unsigned short, h);
}

// softmax done in exp2 domain: fold SCALE * log2(e) into Q at store time
#define QSCALE (0.17677669529663687f * 1.4426950408889634f)

// ---------------------------------------------------------------------------
// Kernel 1: QKV GEMM. A = x gathered by idx (fp32->bf16 at staging),
// B^T = w_qkv (fp32->bf16 at staging). C scattered to per-head Q,K (n-major)
// and V^T (d-major) bf16 buffers. Tile 64x64, K=256 fully staged in LDS.
// grid = (256 M-tiles, 2 N-halves), block = 256 (4 waves, 2x2 of 32x32).
// ---------------------------------------------------------------------------
__global__ __launch_bounds__(256) void qkv_gemm(
    const float* __restrict__ x, const int* __restrict__ idx,
    const float* __restrict__ w_qkv,
    unsigned short* __restrict__ Qb, unsigned short* __restrict__ Kb,
    unsigned short* __restrict__ Vtg)
{
  __shared__ unsigned short Alds[64*256];   // 32 KiB, XOR-swizzled
  __shared__ unsigned short Blds[64*256];   // 32 KiB
  const int tid = threadIdx.x;
  const int m0 = blockIdx.x << 6;
  const int bb = m0 >> 12;          // batch (64 | 1024, uniform per block)
  const int gg = (m0 >> 10) & 3;    // group
  const int j0 = m0 & 4095;         // permuted position base

  // stage A: 64 rows x 256 k, gather rows via idx
  #pragma unroll
  for (int it = 0; it < 8; ++it){
    int c = (it << 8) + tid;             // 2048 chunks of 8 elems
    int row = c >> 5;
    int k8 = (c & 31) << 3;
    int srow = (bb << 12) + idx[j0 + row];
    const float4 f0 = *(const float4*)(x + srow*256 + k8);
    const float4 f1 = *(const float4*)(x + srow*256 + k8 + 4);
    bf16x8 v;
    v[0]=(short)f2bf(f0.x); v[1]=(short)f2bf(f0.y);
    v[2]=(short)f2bf(f0.z); v[3]=(short)f2bf(f0.w);
    v[4]=(short)f2bf(f1.x); v[5]=(short)f2bf(f1.y);
    v[6]=(short)f2bf(f1.z); v[7]=(short)f2bf(f1.w);
    int byt = ((row << 9) + (k8 << 1)) ^ ((row & 7) << 4);
    *(bf16x8*)((char*)Alds + byt) = v;
  }

  const int w  = tid >> 6, lane = tid & 63;
  const int lr = lane & 15, lg = lane >> 4;
  const int wr = w >> 1,  wc = w & 1;

  for (int nt = 0; nt < 6; ++nt){
    const int n0 = blockIdx.y * 384 + nt * 64;
    __syncthreads();     // prev compute done reading Blds (and A visible on nt=0)
    #pragma unroll
    for (int it = 0; it < 8; ++it){
      int c = (it << 8) + tid;
      int row = c >> 5;
      int k8 = (c & 31) << 3;
      const float4 f0 = *(const float4*)(w_qkv + (n0+row)*256 + k8);
      const float4 f1 = *(const float4*)(w_qkv + (n0+row)*256 + k8 + 4);
      bf16x8 v;
      v[0]=(short)f2bf(f0.x); v[1]=(short)f2bf(f0.y);
      v[2]=(short)f2bf(f0.z); v[3]=(short)f2bf(f0.w);
      v[4]=(short)f2bf(f1.x); v[5]=(short)f2bf(f1.y);
      v[6]=(short)f2bf(f1.z); v[7]=(short)f2bf(f1.w);
      int byt = ((row << 9) + (k8 << 1)) ^ ((row & 7) << 4);
      *(bf16x8*)((char*)Blds + byt) = v;
    }
    __syncthreads();

    f32x4 acc[2][2];
    #pragma unroll
    for (int i=0;i<2;++i)
      #pragma unroll
      for (int j=0;j<2;++j)
        acc[i][j] = (f32x4){0.f,0.f,0.f,0.f};

    #pragma unroll
    for (int ks = 0; ks < 8; ++ks){
      bf16x8 af[2], bfr[2];
      int ka = (ks << 5) + (lg << 3);
      #pragma unroll
      for (int i=0;i<2;++i){
        int rowA = (wr << 5) + (i << 4) + lr;
        int bytA = ((rowA << 9) + (ka << 1)) ^ ((rowA & 7) << 4);
        af[i] = *(const bf16x8*)((const char*)Alds + bytA);
        int rowB = (wc << 5) + (i << 4) + lr;
        int bytB = ((rowB << 9) + (ka << 1)) ^ ((rowB & 7) << 4);
        bfr[i] = *(const bf16x8*)((const char*)Blds + bytB);
      }
      #pragma unroll
      for (int i=0;i<2;++i)
        #pragma unroll
        for (int j=0;j<2;++j)
          acc[i][j] = __builtin_amdgcn_mfma_f32_16x16x32_bf16(af[i], bfr[j], acc[i][j], 0, 0, 0);
    }

    // epilogue: D elem (row = lg*4+q, col = lr) per frag
    #pragma unroll
    for (int i=0;i<2;++i){
      int mr0 = m0 + (wr << 5) + (i << 4) + (lg << 2);
      int nl0 = mr0 & 1023;        // position within group-sequence
      #pragma unroll
      for (int j=0;j<2;++j){
        int o = n0 + (wc << 5) + (j << 4) + lr;    // 0..767
        int s = o >> 8, h = (o >> 5) & 7, dd = o & 31;
        int head = ((bb << 2) + gg) * 8 + h;        // 0..127
        if (s == 2){
          // V stored transposed: Vtg[head][dd][n]  (4 consecutive n -> 8B store)
          ushort4 pk;
          pk.x = f2bf(acc[i][j][0]); pk.y = f2bf(acc[i][j][1]);
          pk.z = f2bf(acc[i][j][2]); pk.w = f2bf(acc[i][j][3]);
          *(ushort4*)(Vtg + head*32768 + dd*1024 + nl0) = pk;
        } else {
          unsigned short* dst = (s==0 ? Qb : Kb) + head*32768 + dd;
          float sc = (s==0) ? QSCALE : 1.0f;
          #pragma unroll
          for (int q=0;q<4;++q)
            dst[(nl0+q) << 5] = f2bf(acc[i][j][q] * sc);
        }
      }
    }
  }
}

// ---------------------------------------------------------------------------
// Kernel 2: attention (rewritten R1).
// 1 block = 1 head x 128 q-rows, 8 waves x 16 q-rows, NO LDS (V read direct
// from global V^T -- L2 provides the 64x reuse; Common-mistake #7).
// 64-m tiles: softmax fixed costs amortized over 16 scores/lane.
// Defer-max (T13): rescale path only when tile max grows past mrun+8
// (exp2 domain -> P bounded by 2^8, bf16-safe).
// Swapped QK^T (mfma(K,Q)) + K-row permutation puts S^T frags directly in
// the PV A-operand layout: p[j] = score(q=lr, m = m0 + lg*8 + j).
// grid = 128 heads * 8 qblocks = 1024, block = 512.
// ---------------------------------------------------------------------------
__global__ __launch_bounds__(512, 4) void attn_kernel(
    const unsigned short* __restrict__ Qb, const unsigned short* __restrict__ Kb,
    const unsigned short* __restrict__ Vtg, float* __restrict__ operm)
{
  const int tid  = threadIdx.x;
  const int head = blockIdx.x >> 3;
  const int qblk = blockIdx.x & 7;
  const int w  = tid >> 6, lane = tid & 63;
  const int lr = lane & 15, lg = lane >> 4;
  const int q0 = qblk * 128 + w * 16;

  const unsigned short* qbase = Qb  + head*32768;
  const unsigned short* kbase = Kb  + head*32768;
  const unsigned short* vbase = Vtg + head*32768;

  bf16x8 qf = *(const bf16x8*)(qbase + (q0 + lr)*32 + (lg << 3));  // Q row, hoisted
  const int kperm = ((lr >> 2) << 3) + (lr & 3);   // K-row permutation

  const unsigned short* kp = kbase + kperm*32 + (lg << 3);
  const unsigned short* vp0 = vbase + lr*1024        + (lg << 3);
  const unsigned short* vp1 = vbase + (lr + 16)*1024 + (lg << 3);

  f32x4 o0 = {0.f,0.f,0.f,0.f}, o1 = {0.f,0.f,0.f,0.f};
  float lsum = 0.f;          // per-lane partial denominator (q-row = lr)
  float mrun = -1e30f;       // running max (per q-row, uniform across lg)

  for (int m0 = 0; m0 < 1024; m0 += 64){
    // K fragments (4 x 16B) and V^T fragments (4 x 16B) straight from global
    bf16x8 kA0 = *(const bf16x8*)(kp + (m0     )*32);
    bf16x8 kB0 = *(const bf16x8*)(kp + (m0 +  4)*32);
    bf16x8 kA1 = *(const bf16x8*)(kp + (m0 + 32)*32);
    bf16x8 kB1 = *(const bf16x8*)(kp + (m0 + 36)*32);
    bf16x8 v00 = *(const bf16x8*)(vp0 + m0);
    bf16x8 v10 = *(const bf16x8*)(vp0 + m0 + 32);
    bf16x8 v01 = *(const bf16x8*)(vp1 + m0);
    bf16x8 v11 = *(const bf16x8*)(vp1 + m0 + 32);

    const f32x4 z = {0.f,0.f,0.f,0.f};
    f32x4 sA0 = __builtin_amdgcn_mfma_f32_16x16x32_bf16(kA0, qf, z, 0, 0, 0);
    f32x4 sB0 = __builtin_amdgcn_mfma_f32_16x16x32_bf16(kB0, qf, z, 0, 0, 0);
    f32x4 sA1 = __builtin_amdgcn_mfma_f32_16x16x32_bf16(kA1, qf, z, 0, 0, 0);
    f32x4 sB1 = __builtin_amdgcn_mfma_f32_16x16x32_bf16(kB1, qf, z, 0, 0, 0);

    float p[16];
    p[0]=sA0[0];  p[1]=sA0[1];  p[2]=sA0[2];  p[3]=sA0[3];
    p[4]=sB0[0];  p[5]=sB0[1];  p[6]=sB0[2];  p[7]=sB0[3];
    p[8]=sA1[0];  p[9]=sA1[1];  p[10]=sA1[2]; p[11]=sA1[3];
    p[12]=sB1[0]; p[13]=sB1[1]; p[14]=sB1[2]; p[15]=sB1[3];

    // tile max (per q-row; lanes with same lr agree after the 2 shfls)
    float mt = fmaxf(fmaxf(fmaxf(p[0],p[1]),fmaxf(p[2],p[3])),
                     fmaxf(fmaxf(p[4],p[5]),fmaxf(p[6],p[7])));
    float mt2 = fmaxf(fmaxf(fmaxf(p[8],p[9]),fmaxf(p[10],p[11])),
                      fmaxf(fmaxf(p[12],p[13]),fmaxf(p[14],p[15])));
    mt = fmaxf(mt, mt2);
    mt = fmaxf(mt, __shfl_xor(mt, 16));
    mt = fmaxf(mt, __shfl_xor(mt, 32));

    if (!__all(mt <= mrun + 8.0f)){      // defer-max: rare path
      float mnew = fmaxf(mrun, mt);
      float alpha = exp2f(mrun - mnew);  // per q-row lr (uniform across lg)
      lsum *= alpha;
      // O rows are q = lg*4+reg -> fetch that row's alpha from lane (lg*4+reg)
      float ra0 = __shfl(alpha, (lg << 2) + 0);
      float ra1 = __shfl(alpha, (lg << 2) + 1);
      float ra2 = __shfl(alpha, (lg << 2) + 2);
      float ra3 = __shfl(alpha, (lg << 2) + 3);
      o0[0]*=ra0; o0[1]*=ra1; o0[2]*=ra2; o0[3]*=ra3;
      o1[0]*=ra0; o1[1]*=ra1; o1[2]*=ra2; o1[3]*=ra3;
      mrun = mnew;
    }

    #pragma unroll
    for (int j = 0; j < 16; ++j) p[j] = exp2f(p[j] - mrun);

    lsum += (((p[0]+p[1])+(p[2]+p[3])) + ((p[4]+p[5])+(p[6]+p[7])))
          + (((p[8]+p[9])+(p[10]+p[11])) + ((p[12]+p[13])+(p[14]+p[15])));

    bf16x8 pf0, pf1;
    pf0[0]=(short)f2bf(p[0]);  pf0[1]=(short)f2bf(p[1]);
    pf0[2]=(short)f2bf(p[2]);  pf0[3]=(short)f2bf(p[3]);
    pf0[4]=(short)f2bf(p[4]);  pf0[5]=(short)f2bf(p[5]);
    pf0[6]=(short)f2bf(p[6]);  pf0[7]=(short)f2bf(p[7]);
    pf1[0]=(short)f2bf(p[8]);  pf1[1]=(short)f2bf(p[9]);
    pf1[2]=(short)f2bf(p[10]); pf1[3]=(short)f2bf(p[11]);
    pf1[4]=(short)f2bf(p[12]); pf1[5]=(short)f2bf(p[13]);
    pf1[6]=(short)f2bf(p[14]); pf1[7]=(short)f2bf(p[15]);

    o0 = __builtin_amdgcn_mfma_f32_16x16x32_bf16(pf0, v00, o0, 0, 0, 0);
    o1 = __builtin_amdgcn_mfma_f32_16x16x32_bf16(pf0, v01, o1, 0, 0, 0);
    o0 = __builtin_amdgcn_mfma_f32_16x16x32_bf16(pf1, v10, o0, 0, 0, 0);
    o1 = __builtin_amdgcn_mfma_f32_16x16x32_bf16(pf1, v11, o1, 0, 0, 0);
  }

  // final cross-lane denominator reduce (once, not per tile)
  float ls = lsum + __shfl_xor(lsum, 16);
  ls += __shfl_xor(ls, 32);
  float inv = 1.0f / ls;     // per q-row lr

  const int bI = head >> 5, gI = (head >> 3) & 3, hI = head & 7;
  float* obase = operm + (bI*4096 + gI*1024 + q0)*256 + hI*32;
  #pragma unroll
  for (int q = 0; q < 4; ++q){
    float rq = __shfl(inv, (lg << 2) + q);
    obase[((lg << 2) + q)*256 + lr]      = o0[q] * rq;
    obase[((lg << 2) + q)*256 + 16 + lr] = o1[q] * rq;
  }
}

// ---------------------------------------------------------------------------
// Kernel 3: projection GEMM + bias + inverse-permutation scatter.
// A = operm (fp32->bf16 at staging), B^T = w_proj. out[b, idx[j], :] = row j.
// grid = (256, 2), block = 256.
// ---------------------------------------------------------------------------
__global__ __launch_bounds__(256) void proj_gemm(
    const float* __restrict__ operm, const float* __restrict__ w_proj,
    const float* __restrict__ b_proj, const int* __restrict__ idx,
    float* __restrict__ out)
{
  __shared__ unsigned short Alds[64*256];
  __shared__ unsigned short Blds[64*256];
  const int tid = threadIdx.x;
  const int m0 = blockIdx.x << 6;
  const int bb = m0 >> 12;

  #pragma unroll
  for (int it = 0; it < 8; ++it){
    int c = (it << 8) + tid;
    int row = c >> 5;
    int k8 = (c & 31) << 3;
    const float4 f0 = *(const float4*)(operm + (m0+row)*256 + k8);
    const float4 f1 = *(const float4*)(operm + (m0+row)*256 + k8 + 4);
    bf16x8 v;
    v[0]=(short)f2bf(f0.x); v[1]=(short)f2bf(f0.y);
    v[2]=(short)f2bf(f0.z); v[3]=(short)f2bf(f0.w);
    v[4]=(short)f2bf(f1.x); v[5]=(short)f2bf(f1.y);
    v[6]=(short)f2bf(f1.z); v[7]=(short)f2bf(f1.w);
    int byt = ((row << 9) + (k8 << 1)) ^ ((row & 7) << 4);
    *(bf16x8*)((char*)Alds + byt) = v;
  }

  const int w  = tid >> 6, lane = tid & 63;
  const int lr = lane & 15, lg = lane >> 4;
  const int wr = w >> 1,  wc = w & 1;

  for (int nt = 0; nt < 2; ++nt){
    const int n0 = blockIdx.y * 128 + nt * 64;
    __syncthreads();
    #pragma unroll
    for (int it = 0; it < 8; ++it){
      int c = (it << 8) + tid;
      int row = c >> 5;
      int k8 = (c & 31) << 3;
      const float4 f0 = *(const float4*)(w_proj + (n0+row)*256 + k8);
      const float4 f1 = *(const float4*)(w_proj + (n0+row)*256 + k8 + 4);
      bf16x8 v;
      v[0]=(short)f2bf(f0.x); v[1]=(short)f2bf(f0.y);
      v[2]=(short)f2bf(f0.z); v[3]=(short)f2bf(f0.w);
      v[4]=(short)f2bf(f1.x); v[5]=(short)f2bf(f1.y);
      v[6]=(short)f2bf(f1.z); v[7]=(short)f2bf(f1.w);
      int byt = ((row << 9) + (k8 << 1)) ^ ((row & 7) << 4);
      *(bf16x8*)((char*)Blds + byt) = v;
    }
    __syncthreads();

    f32x4 acc[2][2];
    #pragma unroll
    for (int i=0;i<2;++i)
      #pragma unroll
      for (int j=0;j<2;++j)
        acc[i][j] = (f32x4){0.f,0.f,0.f,0.f};

    #pragma unroll
    for (int ks = 0; ks < 8; ++ks){
      bf16x8 af[2], bfr[2];
      int ka = (ks << 5) + (lg << 3);
      #pragma unroll
      for (int i=0;i<2;++i){
        int rowA = (wr << 5) + (i << 4) + lr;
        int bytA = ((rowA << 9) + (ka << 1)) ^ ((rowA & 7) << 4);
        af[i] = *(const bf16x8*)((const char*)Alds + bytA);
        int rowB = (wc << 5) + (i << 4) + lr;
        int bytB = ((rowB << 9) + (ka << 1)) ^ ((rowB & 7) << 4);
        bfr[i] = *(const bf16x8*)((const char*)Blds + bytB);
      }
      #pragma unroll
      for (int i=0;i<2;++i)
        #pragma unroll
        for (int j=0;j<2;++j)
          acc[i][j] = __builtin_amdgcn_mfma_f32_16x16x32_bf16(af[i], bfr[j], acc[i][j], 0, 0, 0);
    }

    #pragma unroll
    for (int i=0;i<2;++i){
      int mr0 = m0 + (wr << 5) + (i << 4) + (lg << 2);
      int rd[4];
      #pragma unroll
      for (int q=0;q<4;++q)
        rd[q] = (bb << 12) + idx[(mr0 + q) & 4095];   // inverse perm as scatter
      #pragma unroll
      for (int j=0;j<2;++j){
        int o = n0 + (wc << 5) + (j << 4) + lr;
        float bias = b_proj[o];
        #pragma unroll
        for (int q=0;q<4;++q)
          out[rd[q]*256 + o] = acc[i][j][q] + bias;
      }
    }
  }
}

// ---------------------------------------------------------------------------
extern "C" void kernel_launch(void* const* d_in, const int* in_sizes, int n_in,
                              void* d_out, int out_size, void* d_ws, size_t ws_size,
                              hipStream_t stream)
{
  const float* x      = (const float*)d_in[0];
  const int*   idx    = (const int*)  d_in[1];
  const float* w_qkv  = (const float*)d_in[2];
  const float* w_proj = (const float*)d_in[3];
  const float* b_proj = (const float*)d_in[4];
  float* out = (float*)d_out;

  char* ws = (char*)d_ws;
  unsigned short* Qb   = (unsigned short*)(ws);                  // 8 MiB
  unsigned short* Kb   = (unsigned short*)(ws + (8u  << 20));    // 8 MiB
  unsigned short* Vtg  = (unsigned short*)(ws + (16u << 20));    // 8 MiB (transposed)
  float*          operm= (float*)        (ws + (24u << 20));     // 16 MiB

  qkv_gemm<<<dim3(256, 2), 256, 0, stream>>>(x, idx, w_qkv, Qb, Kb, Vtg);
  attn_kernel<<<dim3(1024), 512, 0, stream>>>(Qb, Kb, Vtg, operm);
  proj_gemm<<<dim3(256, 2), 256, 0, stream>>>(operm, w_proj, b_proj, idx, out);
}

// Round 3
// 83.111 us; speedup vs baseline: 1.6996x; 1.6996x over previous
//
#include <hip/hip_runtime.h>
#include <hip/hip_bf16.h>

// Problem constants: B=4, N=4096, C=256, H=8 heads, G=4 groups, d=32, n=1024
// M_TOT = B*N = 16384 rows.

typedef __attribute__((ext_vector_type(8))) short bf16x8;  // 8 bf16 (4 VGPRs)
typedef __attribute__((ext_vector_type(4))) float f32x4;

__device__ __forceinline__ unsigned short f2bf(float x){
  __hip_bfloat16 h = __float2bfloat16(x);   // RNE; pairs fuse to v_cvt_pk_bf16_f32
  return __builtin_bit_cast(unsigned short, h);
}

// softmax done in exp2 domain: fold SCALE * log2(e) into Q at store time
#define QSCALE (0.17677669529663687f * 1.4426950408889634f)

// Fragment-major layouts (produced by qkv_gemm, consumed by attn):
//  KF[head][t][f][lane][e]   : elem = K[32t + perm(lr) + 4f][lg*8+e],
//                              lane = lg*16+lr, perm(lr) = (lr>>2)*8 + (lr&3)
//  VF[head][t][half][lane][e]: elem = V[32t + lg*8 + e][16*half + lr]
// Strides (elems): head 32768, t 1024, f/half 512, lane 8.
// attn stages these LINEARLY to LDS (lane i <-> byte 16i): conflict-free b128.

// ---------------------------------------------------------------------------
// Kernel 1: QKV GEMM. A = x gathered by idx (fp32->bf16 at staging),
// B^T = w_qkv. Tile 64x64, K=256 fully staged in LDS (XOR-swizzled).
// Epilogue scatters to Q (n-major) and fragment-major KF / VF.
// grid = (256 M-tiles, 2 N-halves), block = 256 (4 waves, 2x2 of 32x32).
// ---------------------------------------------------------------------------
__global__ __launch_bounds__(256) void qkv_gemm(
    const float* __restrict__ x, const int* __restrict__ idx,
    const float* __restrict__ w_qkv,
    unsigned short* __restrict__ Qb, unsigned short* __restrict__ KF,
    unsigned short* __restrict__ VF)
{
  __shared__ unsigned short Alds[64*256];   // 32 KiB, XOR-swizzled
  __shared__ unsigned short Blds[64*256];   // 32 KiB
  const int tid = threadIdx.x;
  const int m0 = blockIdx.x << 6;
  const int bb = m0 >> 12;          // batch (uniform per block)
  const int gg = (m0 >> 10) & 3;    // group
  const int j0 = m0 & 4095;         // permuted position base

  // stage A: 64 rows x 256 k, gather rows via idx
  #pragma unroll
  for (int it = 0; it < 8; ++it){
    int c = (it << 8) + tid;             // 2048 chunks of 8 elems
    int row = c >> 5;
    int k8 = (c & 31) << 3;
    int srow = (bb << 12) + idx[j0 + row];
    const float4 f0 = *(const float4*)(x + srow*256 + k8);
    const float4 f1 = *(const float4*)(x + srow*256 + k8 + 4);
    bf16x8 v;
    v[0]=(short)f2bf(f0.x); v[1]=(short)f2bf(f0.y);
    v[2]=(short)f2bf(f0.z); v[3]=(short)f2bf(f0.w);
    v[4]=(short)f2bf(f1.x); v[5]=(short)f2bf(f1.y);
    v[6]=(short)f2bf(f1.z); v[7]=(short)f2bf(f1.w);
    int byt = ((row << 9) + (k8 << 1)) ^ ((row & 7) << 4);
    *(bf16x8*)((char*)Alds + byt) = v;
  }

  const int w  = tid >> 6, lane = tid & 63;
  const int lr = lane & 15, lg = lane >> 4;
  const int wr = w >> 1,  wc = w & 1;

  for (int nt = 0; nt < 6; ++nt){
    const int n0 = blockIdx.y * 384 + nt * 64;
    __syncthreads();     // prev compute done reading Blds (and A visible on nt=0)
    #pragma unroll
    for (int it = 0; it < 8; ++it){
      int c = (it << 8) + tid;
      int row = c >> 5;
      int k8 = (c & 31) << 3;
      const float4 f0 = *(const float4*)(w_qkv + (n0+row)*256 + k8);
      const float4 f1 = *(const float4*)(w_qkv + (n0+row)*256 + k8 + 4);
      bf16x8 v;
      v[0]=(short)f2bf(f0.x); v[1]=(short)f2bf(f0.y);
      v[2]=(short)f2bf(f0.z); v[3]=(short)f2bf(f0.w);
      v[4]=(short)f2bf(f1.x); v[5]=(short)f2bf(f1.y);
      v[6]=(short)f2bf(f1.z); v[7]=(short)f2bf(f1.w);
      int byt = ((row << 9) + (k8 << 1)) ^ ((row & 7) << 4);
      *(bf16x8*)((char*)Blds + byt) = v;
    }
    __syncthreads();

    f32x4 acc[2][2];
    #pragma unroll
    for (int i=0;i<2;++i)
      #pragma unroll
      for (int j=0;j<2;++j)
        acc[i][j] = (f32x4){0.f,0.f,0.f,0.f};

    #pragma unroll
    for (int ks = 0; ks < 8; ++ks){
      bf16x8 af[2], bfr[2];
      int ka = (ks << 5) + (lg << 3);
      #pragma unroll
      for (int i=0;i<2;++i){
        int rowA = (wr << 5) + (i << 4) + lr;
        int bytA = ((rowA << 9) + (ka << 1)) ^ ((rowA & 7) << 4);
        af[i] = *(const bf16x8*)((const char*)Alds + bytA);
        int rowB = (wc << 5) + (i << 4) + lr;
        int bytB = ((rowB << 9) + (ka << 1)) ^ ((rowB & 7) << 4);
        bfr[i] = *(const bf16x8*)((const char*)Blds + bytB);
      }
      #pragma unroll
      for (int i=0;i<2;++i)
        #pragma unroll
        for (int j=0;j<2;++j)
          acc[i][j] = __builtin_amdgcn_mfma_f32_16x16x32_bf16(af[i], bfr[j], acc[i][j], 0, 0, 0);
    }

    // epilogue: D elem (row = lg*4+q, col = lr) per frag
    #pragma unroll
    for (int i=0;i<2;++i){
      int mr0 = m0 + (wr << 5) + (i << 4) + (lg << 2);
      int nl0 = mr0 & 1023;        // position within group-sequence (mult of 4)
      int t   = nl0 >> 5;
      #pragma unroll
      for (int j=0;j<2;++j){
        int o = n0 + (wc << 5) + (j << 4) + lr;    // 0..767
        int s = o >> 8, h = (o >> 5) & 7, dd = o & 31;
        int head = ((bb << 2) + gg) * 8 + h;        // 0..127
        if (s == 2){
          // V fragment-major: one ushort4 (4 consecutive m -> consecutive e)
          int m = nl0 & 31;
          int lane2 = ((m >> 3) << 4) + (dd & 15);
          int half = dd >> 4;
          ushort4 pk;
          pk.x = f2bf(acc[i][j][0]); pk.y = f2bf(acc[i][j][1]);
          pk.z = f2bf(acc[i][j][2]); pk.w = f2bf(acc[i][j][3]);
          *(ushort4*)(VF + head*32768 + t*1024 + half*512 + lane2*8 + (m & 7)) = pk;
        } else if (s == 1){
          // K fragment-major: 4 scalar stores, stride 8 elems (lane advances by q)
          int r0 = nl0 & 31;
          int f  = (r0 >> 2) & 1;
          unsigned short* dst = KF + head*32768 + t*1024 + f*512
                               + ((((dd >> 3) << 4) + ((r0 >> 3) << 2)) << 3) + (dd & 7);
          dst[0]  = f2bf(acc[i][j][0]);
          dst[8]  = f2bf(acc[i][j][1]);
          dst[16] = f2bf(acc[i][j][2]);
          dst[24] = f2bf(acc[i][j][3]);
        } else {
          // Q n-major [head][n][32], QSCALE folded
          unsigned short* dst = Qb + head*32768 + dd;
          #pragma unroll
          for (int q=0;q<4;++q)
            dst[(nl0+q) << 5] = f2bf(acc[i][j][q] * QSCALE);
        }
      }
    }
  }
}

// ---------------------------------------------------------------------------
// Kernel 2: attention (R2). 1 block = 1 head x 128 q-rows, 8 waves x 16 q.
// K AND V staged in LDS from fragment-major global layouts, double-buffered
// 128-m tiles (16 KiB/buf, 32 KiB total). Reg-staged async-split (T14):
// issue next tile's global loads at iter start, ds_write after compute.
// All ds_read_b128 at lane*16 -> conflict-free. Softmax = R1's structure
// (64-m grouping, defer-max T13, per-lane lsum).
// grid = 1024, block = 512.
// ---------------------------------------------------------------------------
__global__ __launch_bounds__(512) void attn_kernel(
    const unsigned short* __restrict__ Qb, const unsigned short* __restrict__ KF,
    const unsigned short* __restrict__ VF, float* __restrict__ operm)
{
  __shared__ __align__(16) char lds[32768];   // [buf 2][K 8KB | V 8KB]
  const int tid  = threadIdx.x;
  const int head = blockIdx.x >> 3;
  const int qblk = blockIdx.x & 7;
  const int w  = tid >> 6, lane = tid & 63;
  const int lr = lane & 15, lg = lane >> 4;
  const int q0 = qblk * 128 + w * 16;

  const unsigned short* kf = KF + head*32768;
  const unsigned short* vf = VF + head*32768;
  const unsigned short* qbase = Qb + head*32768;

  // prologue: stage tile 0 into buf0 (each thread: 16B of K, 16B of V)
  {
    bf16x8 k0 = *(const bf16x8*)(kf + tid*8);
    bf16x8 v0 = *(const bf16x8*)(vf + tid*8);
    *(bf16x8*)(lds + tid*16)        = k0;
    *(bf16x8*)(lds + 8192 + tid*16) = v0;
  }
  bf16x8 qf = *(const bf16x8*)(qbase + (q0 + lr)*32 + (lg << 3));  // Q row, hoisted

  f32x4 o0 = {0.f,0.f,0.f,0.f}, o1 = {0.f,0.f,0.f,0.f};
  float lsum = 0.f;          // per-lane partial denominator (q-row = lr)
  float mrun = -1e30f;       // running max (per q-row, uniform across lg)

  __syncthreads();
  int cur = 0;
  for (int it = 0; it < 8; ++it){
    bf16x8 kreg, vreg;
    const bool pfch = (it < 7);
    if (pfch){   // issue next-tile global loads early; latency hides under compute
      kreg = *(const bf16x8*)(kf + (it+1)*4096 + tid*8);
      vreg = *(const bf16x8*)(vf + (it+1)*4096 + tid*8);
    }

    const char* KL = lds + cur*16384 + lane*16;
    const char* VL = KL + 8192;
    #pragma unroll
    for (int hh = 0; hh < 2; ++hh){          // two 64-m halves of the 128-m tile
      const char* kp_ = KL + hh*4096;
      const char* vp_ = VL + hh*4096;
      bf16x8 kA0 = *(const bf16x8*)(kp_);
      bf16x8 kB0 = *(const bf16x8*)(kp_ + 1024);
      bf16x8 kA1 = *(const bf16x8*)(kp_ + 2048);
      bf16x8 kB1 = *(const bf16x8*)(kp_ + 3072);
      bf16x8 v00 = *(const bf16x8*)(vp_);
      bf16x8 v01 = *(const bf16x8*)(vp_ + 1024);
      bf16x8 v10 = *(const bf16x8*)(vp_ + 2048);
      bf16x8 v11 = *(const bf16x8*)(vp_ + 3072);

      const f32x4 z = {0.f,0.f,0.f,0.f};
      f32x4 sA0 = __builtin_amdgcn_mfma_f32_16x16x32_bf16(kA0, qf, z, 0, 0, 0);
      f32x4 sB0 = __builtin_amdgcn_mfma_f32_16x16x32_bf16(kB0, qf, z, 0, 0, 0);
      f32x4 sA1 = __builtin_amdgcn_mfma_f32_16x16x32_bf16(kA1, qf, z, 0, 0, 0);
      f32x4 sB1 = __builtin_amdgcn_mfma_f32_16x16x32_bf16(kB1, qf, z, 0, 0, 0);

      float p[16];
      p[0]=sA0[0];  p[1]=sA0[1];  p[2]=sA0[2];  p[3]=sA0[3];
      p[4]=sB0[0];  p[5]=sB0[1];  p[6]=sB0[2];  p[7]=sB0[3];
      p[8]=sA1[0];  p[9]=sA1[1];  p[10]=sA1[2]; p[11]=sA1[3];
      p[12]=sB1[0]; p[13]=sB1[1]; p[14]=sB1[2]; p[15]=sB1[3];

      float mt = fmaxf(fmaxf(fmaxf(p[0],p[1]),fmaxf(p[2],p[3])),
                       fmaxf(fmaxf(p[4],p[5]),fmaxf(p[6],p[7])));
      float mt2 = fmaxf(fmaxf(fmaxf(p[8],p[9]),fmaxf(p[10],p[11])),
                        fmaxf(fmaxf(p[12],p[13]),fmaxf(p[14],p[15])));
      mt = fmaxf(mt, mt2);
      mt = fmaxf(mt, __shfl_xor(mt, 16));
      mt = fmaxf(mt, __shfl_xor(mt, 32));

      if (!__all(mt <= mrun + 8.0f)){      // defer-max: rare path
        float mnew = fmaxf(mrun, mt);
        float alpha = exp2f(mrun - mnew);  // per q-row lr (uniform across lg)
        lsum *= alpha;
        float ra0 = __shfl(alpha, (lg << 2) + 0);
        float ra1 = __shfl(alpha, (lg << 2) + 1);
        float ra2 = __shfl(alpha, (lg << 2) + 2);
        float ra3 = __shfl(alpha, (lg << 2) + 3);
        o0[0]*=ra0; o0[1]*=ra1; o0[2]*=ra2; o0[3]*=ra3;
        o1[0]*=ra0; o1[1]*=ra1; o1[2]*=ra2; o1[3]*=ra3;
        mrun = mnew;
      }

      #pragma unroll
      for (int j = 0; j < 16; ++j) p[j] = exp2f(p[j] - mrun);

      lsum += (((p[0]+p[1])+(p[2]+p[3])) + ((p[4]+p[5])+(p[6]+p[7])))
            + (((p[8]+p[9])+(p[10]+p[11])) + ((p[12]+p[13])+(p[14]+p[15])));

      bf16x8 pf0, pf1;
      pf0[0]=(short)f2bf(p[0]);  pf0[1]=(short)f2bf(p[1]);
      pf0[2]=(short)f2bf(p[2]);  pf0[3]=(short)f2bf(p[3]);
      pf0[4]=(short)f2bf(p[4]);  pf0[5]=(short)f2bf(p[5]);
      pf0[6]=(short)f2bf(p[6]);  pf0[7]=(short)f2bf(p[7]);
      pf1[0]=(short)f2bf(p[8]);  pf1[1]=(short)f2bf(p[9]);
      pf1[2]=(short)f2bf(p[10]); pf1[3]=(short)f2bf(p[11]);
      pf1[4]=(short)f2bf(p[12]); pf1[5]=(short)f2bf(p[13]);
      pf1[6]=(short)f2bf(p[14]); pf1[7]=(short)f2bf(p[15]);

      o0 = __builtin_amdgcn_mfma_f32_16x16x32_bf16(pf0, v00, o0, 0, 0, 0);
      o1 = __builtin_amdgcn_mfma_f32_16x16x32_bf16(pf0, v01, o1, 0, 0, 0);
      o0 = __builtin_amdgcn_mfma_f32_16x16x32_bf16(pf1, v10, o0, 0, 0, 0);
      o1 = __builtin_amdgcn_mfma_f32_16x16x32_bf16(pf1, v11, o1, 0, 0, 0);
    }

    if (pfch){   // write staged regs into the other buffer (T14 write-late)
      char* db = lds + (cur^1)*16384;
      *(bf16x8*)(db + tid*16)        = kreg;
      *(bf16x8*)(db + 8192 + tid*16) = vreg;
    }
    __syncthreads();
    cur ^= 1;
  }

  // final cross-lane denominator reduce (once, not per tile)
  float ls = lsum + __shfl_xor(lsum, 16);
  ls += __shfl_xor(ls, 32);
  float inv = 1.0f / ls;     // per q-row lr

  const int bI = head >> 5, gI = (head >> 3) & 3, hI = head & 7;
  float* obase = operm + (bI*4096 + gI*1024 + q0)*256 + hI*32;
  #pragma unroll
  for (int q = 0; q < 4; ++q){
    float rq = __shfl(inv, (lg << 2) + q);
    obase[((lg << 2) + q)*256 + lr]      = o0[q] * rq;
    obase[((lg << 2) + q)*256 + 16 + lr] = o1[q] * rq;
  }
}

// ---------------------------------------------------------------------------
// Kernel 3: projection GEMM + bias + inverse-permutation scatter.
// A = operm (fp32->bf16 at staging), B^T = w_proj. out[b, idx[j], :] = row j.
// grid = (256, 2), block = 256.
// ---------------------------------------------------------------------------
__global__ __launch_bounds__(256) void proj_gemm(
    const float* __restrict__ operm, const float* __restrict__ w_proj,
    const float* __restrict__ b_proj, const int* __restrict__ idx,
    float* __restrict__ out)
{
  __shared__ unsigned short Alds[64*256];
  __shared__ unsigned short Blds[64*256];
  const int tid = threadIdx.x;
  const int m0 = blockIdx.x << 6;
  const int bb = m0 >> 12;

  #pragma unroll
  for (int it = 0; it < 8; ++it){
    int c = (it << 8) + tid;
    int row = c >> 5;
    int k8 = (c & 31) << 3;
    const float4 f0 = *(const float4*)(operm + (m0+row)*256 + k8);
    const float4 f1 = *(const float4*)(operm + (m0+row)*256 + k8 + 4);
    bf16x8 v;
    v[0]=(short)f2bf(f0.x); v[1]=(short)f2bf(f0.y);
    v[2]=(short)f2bf(f0.z); v[3]=(short)f2bf(f0.w);
    v[4]=(short)f2bf(f1.x); v[5]=(short)f2bf(f1.y);
    v[6]=(short)f2bf(f1.z); v[7]=(short)f2bf(f1.w);
    int byt = ((row << 9) + (k8 << 1)) ^ ((row & 7) << 4);
    *(bf16x8*)((char*)Alds + byt) = v;
  }

  const int w  = tid >> 6, lane = tid & 63;
  const int lr = lane & 15, lg = lane >> 4;
  const int wr = w >> 1,  wc = w & 1;

  for (int nt = 0; nt < 2; ++nt){
    const int n0 = blockIdx.y * 128 + nt * 64;
    __syncthreads();
    #pragma unroll
    for (int it = 0; it < 8; ++it){
      int c = (it << 8) + tid;
      int row = c >> 5;
      int k8 = (c & 31) << 3;
      const float4 f0 = *(const float4*)(w_proj + (n0+row)*256 + k8);
      const float4 f1 = *(const float4*)(w_proj + (n0+row)*256 + k8 + 4);
      bf16x8 v;
      v[0]=(short)f2bf(f0.x); v[1]=(short)f2bf(f0.y);
      v[2]=(short)f2bf(f0.z); v[3]=(short)f2bf(f0.w);
      v[4]=(short)f2bf(f1.x); v[5]=(short)f2bf(f1.y);
      v[6]=(short)f2bf(f1.z); v[7]=(short)f2bf(f1.w);
      int byt = ((row << 9) + (k8 << 1)) ^ ((row & 7) << 4);
      *(bf16x8*)((char*)Blds + byt) = v;
    }
    __syncthreads();

    f32x4 acc[2][2];
    #pragma unroll
    for (int i=0;i<2;++i)
      #pragma unroll
      for (int j=0;j<2;++j)
        acc[i][j] = (f32x4){0.f,0.f,0.f,0.f};

    #pragma unroll
    for (int ks = 0; ks < 8; ++ks){
      bf16x8 af[2], bfr[2];
      int ka = (ks << 5) + (lg << 3);
      #pragma unroll
      for (int i=0;i<2;++i){
        int rowA = (wr << 5) + (i << 4) + lr;
        int bytA = ((rowA << 9) + (ka << 1)) ^ ((rowA & 7) << 4);
        af[i] = *(const bf16x8*)((const char*)Alds + bytA);
        int rowB = (wc << 5) + (i << 4) + lr;
        int bytB = ((rowB << 9) + (ka << 1)) ^ ((rowB & 7) << 4);
        bfr[i] = *(const bf16x8*)((const char*)Blds + bytB);
      }
      #pragma unroll
      for (int i=0;i<2;++i)
        #pragma unroll
        for (int j=0;j<2;++j)
          acc[i][j] = __builtin_amdgcn_mfma_f32_16x16x32_bf16(af[i], bfr[j], acc[i][j], 0, 0, 0);
    }

    #pragma unroll
    for (int i=0;i<2;++i){
      int mr0 = m0 + (wr << 5) + (i << 4) + (lg << 2);
      int rd[4];
      #pragma unroll
      for (int q=0;q<4;++q)
        rd[q] = (bb << 12) + idx[(mr0 + q) & 4095];   // inverse perm as scatter
      #pragma unroll
      for (int j=0;j<2;++j){
        int o = n0 + (wc << 5) + (j << 4) + lr;
        float bias = b_proj[o];
        #pragma unroll
        for (int q=0;q<4;++q)
          out[rd[q]*256 + o] = acc[i][j][q] + bias;
      }
    }
  }
}

// ---------------------------------------------------------------------------
extern "C" void kernel_launch(void* const* d_in, const int* in_sizes, int n_in,
                              void* d_out, int out_size, void* d_ws, size_t ws_size,
                              hipStream_t stream)
{
  const float* x      = (const float*)d_in[0];
  const int*   idx    = (const int*)  d_in[1];
  const float* w_qkv  = (const float*)d_in[2];
  const float* w_proj = (const float*)d_in[3];
  const float* b_proj = (const float*)d_in[4];
  float* out = (float*)d_out;

  char* ws = (char*)d_ws;
  unsigned short* Qb   = (unsigned short*)(ws);                  // 8 MiB
  unsigned short* KF   = (unsigned short*)(ws + (8u  << 20));    // 8 MiB (frag-major)
  unsigned short* VF   = (unsigned short*)(ws + (16u << 20));    // 8 MiB (frag-major)
  float*          operm= (float*)        (ws + (24u << 20));     // 16 MiB

  qkv_gemm<<<dim3(256, 2), 256, 0, stream>>>(x, idx, w_qkv, Qb, KF, VF);
  attn_kernel<<<dim3(1024), 512, 0, stream>>>(Qb, KF, VF, operm);
  proj_gemm<<<dim3(256, 2), 256, 0, stream>>>(operm, w_proj, b_proj, idx, out);
}

// Round 4
// 71.515 us; speedup vs baseline: 1.9751x; 1.1621x over previous
//
#include <hip/hip_runtime.h>
#include <hip/hip_bf16.h>

// Problem constants: B=4, N=4096, C=256, H=8 heads, G=4 groups, d=32, n=1024
// M_TOT = B*N = 16384 rows.

typedef __attribute__((ext_vector_type(8))) short bf16x8;  // 8 bf16 (4 VGPRs)
typedef __attribute__((ext_vector_type(4))) float f32x4;

__device__ __forceinline__ unsigned short f2bf(float x){
  __hip_bfloat16 h = __float2bfloat16(x);   // RNE; pairs fuse to v_cvt_pk_bf16_f32
  return __builtin_bit_cast(unsigned short, h);
}

// softmax done in exp2 domain: fold SCALE * log2(e) into Q at store time
#define QSCALE (0.17677669529663687f * 1.4426950408889634f)

// Fragment-major layouts (produced by qkv_gemm, consumed by attn):
//  KF[head][t][f][lane][e]   : elem = K[32t + perm(lr) + 4f][lg*8+e],
//                              lane = lg*16+lr, perm(lr) = (lr>>2)*8 + (lr&3)
//  VF[head][t][half][lane][e]: elem = V[32t + lg*8 + e][16*half + lr]
// Strides (elems): head 32768, t 1024, f/half 512, lane 8.
// attn stages these LINEARLY to LDS (lane i <-> byte 16i): conflict-free b128.

// ---------------------------------------------------------------------------
// Kernel 1: QKV GEMM. (unchanged from R2)
// ---------------------------------------------------------------------------
__global__ __launch_bounds__(256) void qkv_gemm(
    const float* __restrict__ x, const int* __restrict__ idx,
    const float* __restrict__ w_qkv,
    unsigned short* __restrict__ Qb, unsigned short* __restrict__ KF,
    unsigned short* __restrict__ VF)
{
  __shared__ unsigned short Alds[64*256];   // 32 KiB, XOR-swizzled
  __shared__ unsigned short Blds[64*256];   // 32 KiB
  const int tid = threadIdx.x;
  const int m0 = blockIdx.x << 6;
  const int bb = m0 >> 12;          // batch (uniform per block)
  const int gg = (m0 >> 10) & 3;    // group
  const int j0 = m0 & 4095;         // permuted position base

  // stage A: 64 rows x 256 k, gather rows via idx
  #pragma unroll
  for (int it = 0; it < 8; ++it){
    int c = (it << 8) + tid;             // 2048 chunks of 8 elems
    int row = c >> 5;
    int k8 = (c & 31) << 3;
    int srow = (bb << 12) + idx[j0 + row];
    const float4 f0 = *(const float4*)(x + srow*256 + k8);
    const float4 f1 = *(const float4*)(x + srow*256 + k8 + 4);
    bf16x8 v;
    v[0]=(short)f2bf(f0.x); v[1]=(short)f2bf(f0.y);
    v[2]=(short)f2bf(f0.z); v[3]=(short)f2bf(f0.w);
    v[4]=(short)f2bf(f1.x); v[5]=(short)f2bf(f1.y);
    v[6]=(short)f2bf(f1.z); v[7]=(short)f2bf(f1.w);
    int byt = ((row << 9) + (k8 << 1)) ^ ((row & 7) << 4);
    *(bf16x8*)((char*)Alds + byt) = v;
  }

  const int w  = tid >> 6, lane = tid & 63;
  const int lr = lane & 15, lg = lane >> 4;
  const int wr = w >> 1,  wc = w & 1;

  for (int nt = 0; nt < 6; ++nt){
    const int n0 = blockIdx.y * 384 + nt * 64;
    __syncthreads();     // prev compute done reading Blds (and A visible on nt=0)
    #pragma unroll
    for (int it = 0; it < 8; ++it){
      int c = (it << 8) + tid;
      int row = c >> 5;
      int k8 = (c & 31) << 3;
      const float4 f0 = *(const float4*)(w_qkv + (n0+row)*256 + k8);
      const float4 f1 = *(const float4*)(w_qkv + (n0+row)*256 + k8 + 4);
      bf16x8 v;
      v[0]=(short)f2bf(f0.x); v[1]=(short)f2bf(f0.y);
      v[2]=(short)f2bf(f0.z); v[3]=(short)f2bf(f0.w);
      v[4]=(short)f2bf(f1.x); v[5]=(short)f2bf(f1.y);
      v[6]=(short)f2bf(f1.z); v[7]=(short)f2bf(f1.w);
      int byt = ((row << 9) + (k8 << 1)) ^ ((row & 7) << 4);
      *(bf16x8*)((char*)Blds + byt) = v;
    }
    __syncthreads();

    f32x4 acc[2][2];
    #pragma unroll
    for (int i=0;i<2;++i)
      #pragma unroll
      for (int j=0;j<2;++j)
        acc[i][j] = (f32x4){0.f,0.f,0.f,0.f};

    #pragma unroll
    for (int ks = 0; ks < 8; ++ks){
      bf16x8 af[2], bfr[2];
      int ka = (ks << 5) + (lg << 3);
      #pragma unroll
      for (int i=0;i<2;++i){
        int rowA = (wr << 5) + (i << 4) + lr;
        int bytA = ((rowA << 9) + (ka << 1)) ^ ((rowA & 7) << 4);
        af[i] = *(const bf16x8*)((const char*)Alds + bytA);
        int rowB = (wc << 5) + (i << 4) + lr;
        int bytB = ((rowB << 9) + (ka << 1)) ^ ((rowB & 7) << 4);
        bfr[i] = *(const bf16x8*)((const char*)Blds + bytB);
      }
      #pragma unroll
      for (int i=0;i<2;++i)
        #pragma unroll
        for (int j=0;j<2;++j)
          acc[i][j] = __builtin_amdgcn_mfma_f32_16x16x32_bf16(af[i], bfr[j], acc[i][j], 0, 0, 0);
    }

    // epilogue: D elem (row = lg*4+q, col = lr) per frag
    #pragma unroll
    for (int i=0;i<2;++i){
      int mr0 = m0 + (wr << 5) + (i << 4) + (lg << 2);
      int nl0 = mr0 & 1023;        // position within group-sequence (mult of 4)
      int t   = nl0 >> 5;
      #pragma unroll
      for (int j=0;j<2;++j){
        int o = n0 + (wc << 5) + (j << 4) + lr;    // 0..767
        int s = o >> 8, h = (o >> 5) & 7, dd = o & 31;
        int head = ((bb << 2) + gg) * 8 + h;        // 0..127
        if (s == 2){
          // V fragment-major: one ushort4 (4 consecutive m -> consecutive e)
          int m = nl0 & 31;
          int lane2 = ((m >> 3) << 4) + (dd & 15);
          int half = dd >> 4;
          ushort4 pk;
          pk.x = f2bf(acc[i][j][0]); pk.y = f2bf(acc[i][j][1]);
          pk.z = f2bf(acc[i][j][2]); pk.w = f2bf(acc[i][j][3]);
          *(ushort4*)(VF + head*32768 + t*1024 + half*512 + lane2*8 + (m & 7)) = pk;
        } else if (s == 1){
          // K fragment-major: 4 scalar stores, stride 8 elems (lane advances by q)
          int r0 = nl0 & 31;
          int f  = (r0 >> 2) & 1;
          unsigned short* dst = KF + head*32768 + t*1024 + f*512
                               + ((((dd >> 3) << 4) + ((r0 >> 3) << 2)) << 3) + (dd & 7);
          dst[0]  = f2bf(acc[i][j][0]);
          dst[8]  = f2bf(acc[i][j][1]);
          dst[16] = f2bf(acc[i][j][2]);
          dst[24] = f2bf(acc[i][j][3]);
        } else {
          // Q n-major [head][n][32], QSCALE folded
          unsigned short* dst = Qb + head*32768 + dd;
          #pragma unroll
          for (int q=0;q<4;++q)
            dst[(nl0+q) << 5] = f2bf(acc[i][j][q] * QSCALE);
        }
      }
    }
  }
}

// ---------------------------------------------------------------------------
// softmax over 16 scores/lane (one q-group), defer-max anchored at 0.
// Scores arrive with -mrun pre-folded (QK MFMA C-operand = mz = splat(-mrun)).
// Fast path: per-lane max check only (no cross-lane). Rare path: cross-lane
// row max, rescale O/lsum, shift mz.
// ---------------------------------------------------------------------------
__device__ __forceinline__ void softmax16(
    const f32x4 s0, const f32x4 s1, const f32x4 s2, const f32x4 s3,
    f32x4& mz, float& lsum, f32x4& o0, f32x4& o1,
    const int lg, bf16x8& pf0, bf16x8& pf1)
{
  float p0=s0[0],  p1=s0[1],  p2=s0[2],  p3=s0[3];
  float p4=s1[0],  p5=s1[1],  p6=s1[2],  p7=s1[3];
  float p8=s2[0],  p9=s2[1],  p10=s2[2], p11=s2[3];
  float p12=s3[0], p13=s3[1], p14=s3[2], p15=s3[3];

  // per-lane max, max3-shaped (5 max3 + 2 max3 + 1 max)
  float ma = fmaxf(fmaxf(p0,p1),p2);
  float mb = fmaxf(fmaxf(p3,p4),p5);
  float mc = fmaxf(fmaxf(p6,p7),p8);
  float md = fmaxf(fmaxf(p9,p10),p11);
  float me = fmaxf(fmaxf(p12,p13),p14);
  float mt = fmaxf(fmaxf(fmaxf(ma,mb),fmaxf(mc,md)), fmaxf(me,p15));

  if (!__all(mt <= 8.0f)){                 // defer-max trigger (rare)
    float mr = fmaxf(mt, __shfl_xor(mt, 16));
    mr = fmaxf(mr, __shfl_xor(mr, 32));    // row max (uniform per q-row)
    float d = fmaxf(mr, 0.0f);             // keep anchor monotonic
    float alpha = __builtin_amdgcn_exp2f(-d);
    lsum *= alpha;
    float ra0 = __shfl(alpha, (lg << 2) + 0);
    float ra1 = __shfl(alpha, (lg << 2) + 1);
    float ra2 = __shfl(alpha, (lg << 2) + 2);
    float ra3 = __shfl(alpha, (lg << 2) + 3);
    o0[0]*=ra0; o0[1]*=ra1; o0[2]*=ra2; o0[3]*=ra3;
    o1[0]*=ra0; o1[1]*=ra1; o1[2]*=ra2; o1[3]*=ra3;
    mz[0]-=d; mz[1]-=d; mz[2]-=d; mz[3]-=d;
    p0-=d;p1-=d;p2-=d;p3-=d;p4-=d;p5-=d;p6-=d;p7-=d;
    p8-=d;p9-=d;p10-=d;p11-=d;p12-=d;p13-=d;p14-=d;p15-=d;
  }

  p0=__builtin_amdgcn_exp2f(p0);   p1=__builtin_amdgcn_exp2f(p1);
  p2=__builtin_amdgcn_exp2f(p2);   p3=__builtin_amdgcn_exp2f(p3);
  p4=__builtin_amdgcn_exp2f(p4);   p5=__builtin_amdgcn_exp2f(p5);
  p6=__builtin_amdgcn_exp2f(p6);   p7=__builtin_amdgcn_exp2f(p7);
  p8=__builtin_amdgcn_exp2f(p8);   p9=__builtin_amdgcn_exp2f(p9);
  p10=__builtin_amdgcn_exp2f(p10); p11=__builtin_amdgcn_exp2f(p11);
  p12=__builtin_amdgcn_exp2f(p12); p13=__builtin_amdgcn_exp2f(p13);
  p14=__builtin_amdgcn_exp2f(p14); p15=__builtin_amdgcn_exp2f(p15);

  lsum += (((p0+p1)+(p2+p3)) + ((p4+p5)+(p6+p7)))
        + (((p8+p9)+(p10+p11)) + ((p12+p13)+(p14+p15)));

  pf0[0]=(short)f2bf(p0);  pf0[1]=(short)f2bf(p1);
  pf0[2]=(short)f2bf(p2);  pf0[3]=(short)f2bf(p3);
  pf0[4]=(short)f2bf(p4);  pf0[5]=(short)f2bf(p5);
  pf0[6]=(short)f2bf(p6);  pf0[7]=(short)f2bf(p7);
  pf1[0]=(short)f2bf(p8);  pf1[1]=(short)f2bf(p9);
  pf1[2]=(short)f2bf(p10); pf1[3]=(short)f2bf(p11);
  pf1[4]=(short)f2bf(p12); pf1[5]=(short)f2bf(p13);
  pf1[6]=(short)f2bf(p14); pf1[7]=(short)f2bf(p15);
}

// ---------------------------------------------------------------------------
// Kernel 2: attention (R3). 1 block = 1 head x 128 q-rows, 4 waves x 32 q.
// Each wave holds TWO Q fragments (rows lr and lr+16): K/V LDS reads are
// shared across both q-groups -> LDS traffic per score halved vs R2.
// Double-buffered 128-m tiles, reg-staged async-split. QK MFMA C-seeded
// with mz = splat(-mrun): no per-score subtract. Raw v_exp_f32.
// grid = 1024, block = 256.
// ---------------------------------------------------------------------------
__global__ __launch_bounds__(256, 4) void attn_kernel(
    const unsigned short* __restrict__ Qb, const unsigned short* __restrict__ KF,
    const unsigned short* __restrict__ VF, float* __restrict__ operm)
{
  __shared__ __align__(16) char lds[32768];   // [buf 2][K 8KB | V 8KB]
  const int tid  = threadIdx.x;
  const int head = blockIdx.x >> 3;
  const int qblk = blockIdx.x & 7;
  const int lane = tid & 63;
  const int w  = tid >> 6;
  const int lr = lane & 15, lg = lane >> 4;
  const int q0 = qblk * 128 + w * 32;

  const unsigned short* kf = KF + head*32768;
  const unsigned short* vf = VF + head*32768;
  const unsigned short* qbase = Qb + head*32768;

  // prologue: stage tile 0 into buf0 (each thread: 2x16B K, 2x16B V)
  {
    bf16x8 k0 = *(const bf16x8*)(kf + tid*8);
    bf16x8 k1 = *(const bf16x8*)(kf + 2048 + tid*8);
    bf16x8 v0 = *(const bf16x8*)(vf + tid*8);
    bf16x8 v1 = *(const bf16x8*)(vf + 2048 + tid*8);
    *(bf16x8*)(lds + tid*16)          = k0;
    *(bf16x8*)(lds + 4096 + tid*16)   = k1;
    *(bf16x8*)(lds + 8192 + tid*16)   = v0;
    *(bf16x8*)(lds + 12288 + tid*16)  = v1;
  }
  bf16x8 qfA = *(const bf16x8*)(qbase + (q0 + lr)*32 + (lg << 3));
  bf16x8 qfB = *(const bf16x8*)(qbase + (q0 + 16 + lr)*32 + (lg << 3));

  f32x4 o0A={0.f,0.f,0.f,0.f}, o1A={0.f,0.f,0.f,0.f};
  f32x4 o0B={0.f,0.f,0.f,0.f}, o1B={0.f,0.f,0.f,0.f};
  f32x4 mzA={0.f,0.f,0.f,0.f}, mzB={0.f,0.f,0.f,0.f};  // -mrun splat (anchor 0)
  float lsA = 0.f, lsB = 0.f;

  __syncthreads();
  int cur = 0;
  for (int it = 0; it < 8; ++it){
    bf16x8 kr0, kr1, vr0, vr1;
    const bool pf = (it < 7);
    if (pf){   // issue next-tile global loads early; latency hides under compute
      const unsigned short* kg = kf + (it+1)*4096 + tid*8;
      const unsigned short* vg = vf + (it+1)*4096 + tid*8;
      kr0 = *(const bf16x8*)(kg);
      kr1 = *(const bf16x8*)(kg + 2048);
      vr0 = *(const bf16x8*)(vg);
      vr1 = *(const bf16x8*)(vg + 2048);
    }

    const char* KL = lds + cur*16384 + lane*16;
    const char* VL = KL + 8192;
    #pragma unroll
    for (int hh = 0; hh < 2; ++hh){          // two 64-m halves of the 128-m tile
      const char* kp_ = KL + hh*4096;
      const char* vp_ = VL + hh*4096;
      bf16x8 kA0 = *(const bf16x8*)(kp_);
      bf16x8 kB0 = *(const bf16x8*)(kp_ + 1024);
      bf16x8 kA1 = *(const bf16x8*)(kp_ + 2048);
      bf16x8 kB1 = *(const bf16x8*)(kp_ + 3072);
      bf16x8 v00 = *(const bf16x8*)(vp_);
      bf16x8 v01 = *(const bf16x8*)(vp_ + 1024);
      bf16x8 v10 = *(const bf16x8*)(vp_ + 2048);
      bf16x8 v11 = *(const bf16x8*)(vp_ + 3072);

      __builtin_amdgcn_s_setprio(1);
      f32x4 sA0A = __builtin_amdgcn_mfma_f32_16x16x32_bf16(kA0, qfA, mzA, 0, 0, 0);
      f32x4 sB0A = __builtin_amdgcn_mfma_f32_16x16x32_bf16(kB0, qfA, mzA, 0, 0, 0);
      f32x4 sA1A = __builtin_amdgcn_mfma_f32_16x16x32_bf16(kA1, qfA, mzA, 0, 0, 0);
      f32x4 sB1A = __builtin_amdgcn_mfma_f32_16x16x32_bf16(kB1, qfA, mzA, 0, 0, 0);
      f32x4 sA0B = __builtin_amdgcn_mfma_f32_16x16x32_bf16(kA0, qfB, mzB, 0, 0, 0);
      f32x4 sB0B = __builtin_amdgcn_mfma_f32_16x16x32_bf16(kB0, qfB, mzB, 0, 0, 0);
      f32x4 sA1B = __builtin_amdgcn_mfma_f32_16x16x32_bf16(kA1, qfB, mzB, 0, 0, 0);
      f32x4 sB1B = __builtin_amdgcn_mfma_f32_16x16x32_bf16(kB1, qfB, mzB, 0, 0, 0);
      __builtin_amdgcn_s_setprio(0);

      bf16x8 pf0A, pf1A, pf0B, pf1B;
      softmax16(sA0A, sB0A, sA1A, sB1A, mzA, lsA, o0A, o1A, lg, pf0A, pf1A);
      softmax16(sA0B, sB0B, sA1B, sB1B, mzB, lsB, o0B, o1B, lg, pf0B, pf1B);

      __builtin_amdgcn_s_setprio(1);
      o0A = __builtin_amdgcn_mfma_f32_16x16x32_bf16(pf0A, v00, o0A, 0, 0, 0);
      o1A = __builtin_amdgcn_mfma_f32_16x16x32_bf16(pf0A, v01, o1A, 0, 0, 0);
      o0A = __builtin_amdgcn_mfma_f32_16x16x32_bf16(pf1A, v10, o0A, 0, 0, 0);
      o1A = __builtin_amdgcn_mfma_f32_16x16x32_bf16(pf1A, v11, o1A, 0, 0, 0);
      o0B = __builtin_amdgcn_mfma_f32_16x16x32_bf16(pf0B, v00, o0B, 0, 0, 0);
      o1B = __builtin_amdgcn_mfma_f32_16x16x32_bf16(pf0B, v01, o1B, 0, 0, 0);
      o0B = __builtin_amdgcn_mfma_f32_16x16x32_bf16(pf1B, v10, o0B, 0, 0, 0);
      o1B = __builtin_amdgcn_mfma_f32_16x16x32_bf16(pf1B, v11, o1B, 0, 0, 0);
      __builtin_amdgcn_s_setprio(0);
    }

    if (pf){   // write staged regs into the other buffer (T14 write-late)
      char* db = lds + (cur^1)*16384;
      *(bf16x8*)(db + tid*16)          = kr0;
      *(bf16x8*)(db + 4096 + tid*16)   = kr1;
      *(bf16x8*)(db + 8192 + tid*16)   = vr0;
      *(bf16x8*)(db + 12288 + tid*16)  = vr1;
    }
    __syncthreads();
    cur ^= 1;
  }

  // final cross-lane denominator reduce (once)
  float lA = lsA + __shfl_xor(lsA, 16); lA += __shfl_xor(lA, 32);
  float lB = lsB + __shfl_xor(lsB, 16); lB += __shfl_xor(lB, 32);
  float invA = 1.0f / lA;
  float invB = 1.0f / lB;

  const int bI = head >> 5, gI = (head >> 3) & 3, hI = head & 7;
  float* obase = operm + (bI*4096 + gI*1024 + q0)*256 + hI*32;
  #pragma unroll
  for (int q = 0; q < 4; ++q){
    float rqA = __shfl(invA, (lg << 2) + q);
    obase[((lg << 2) + q)*256 + lr]        = o0A[q] * rqA;
    obase[((lg << 2) + q)*256 + 16 + lr]   = o1A[q] * rqA;
    float rqB = __shfl(invB, (lg << 2) + q);
    obase[(16 + (lg << 2) + q)*256 + lr]      = o0B[q] * rqB;
    obase[(16 + (lg << 2) + q)*256 + 16 + lr] = o1B[q] * rqB;
  }
}

// ---------------------------------------------------------------------------
// Kernel 3: projection GEMM + bias + inverse-permutation scatter. (unchanged)
// ---------------------------------------------------------------------------
__global__ __launch_bounds__(256) void proj_gemm(
    const float* __restrict__ operm, const float* __restrict__ w_proj,
    const float* __restrict__ b_proj, const int* __restrict__ idx,
    float* __restrict__ out)
{
  __shared__ unsigned short Alds[64*256];
  __shared__ unsigned short Blds[64*256];
  const int tid = threadIdx.x;
  const int m0 = blockIdx.x << 6;
  const int bb = m0 >> 12;

  #pragma unroll
  for (int it = 0; it < 8; ++it){
    int c = (it << 8) + tid;
    int row = c >> 5;
    int k8 = (c & 31) << 3;
    const float4 f0 = *(const float4*)(operm + (m0+row)*256 + k8);
    const float4 f1 = *(const float4*)(operm + (m0+row)*256 + k8 + 4);
    bf16x8 v;
    v[0]=(short)f2bf(f0.x); v[1]=(short)f2bf(f0.y);
    v[2]=(short)f2bf(f0.z); v[3]=(short)f2bf(f0.w);
    v[4]=(short)f2bf(f1.x); v[5]=(short)f2bf(f1.y);
    v[6]=(short)f2bf(f1.z); v[7]=(short)f2bf(f1.w);
    int byt = ((row << 9) + (k8 << 1)) ^ ((row & 7) << 4);
    *(bf16x8*)((char*)Alds + byt) = v;
  }

  const int w  = tid >> 6, lane = tid & 63;
  const int lr = lane & 15, lg = lane >> 4;
  const int wr = w >> 1,  wc = w & 1;

  for (int nt = 0; nt < 2; ++nt){
    const int n0 = blockIdx.y * 128 + nt * 64;
    __syncthreads();
    #pragma unroll
    for (int it = 0; it < 8; ++it){
      int c = (it << 8) + tid;
      int row = c >> 5;
      int k8 = (c & 31) << 3;
      const float4 f0 = *(const float4*)(w_proj + (n0+row)*256 + k8);
      const float4 f1 = *(const float4*)(w_proj + (n0+row)*256 + k8 + 4);
      bf16x8 v;
      v[0]=(short)f2bf(f0.x); v[1]=(short)f2bf(f0.y);
      v[2]=(short)f2bf(f0.z); v[3]=(short)f2bf(f0.w);
      v[4]=(short)f2bf(f1.x); v[5]=(short)f2bf(f1.y);
      v[6]=(short)f2bf(f1.z); v[7]=(short)f2bf(f1.w);
      int byt = ((row << 9) + (k8 << 1)) ^ ((row & 7) << 4);
      *(bf16x8*)((char*)Blds + byt) = v;
    }
    __syncthreads();

    f32x4 acc[2][2];
    #pragma unroll
    for (int i=0;i<2;++i)
      #pragma unroll
      for (int j=0;j<2;++j)
        acc[i][j] = (f32x4){0.f,0.f,0.f,0.f};

    #pragma unroll
    for (int ks = 0; ks < 8; ++ks){
      bf16x8 af[2], bfr[2];
      int ka = (ks << 5) + (lg << 3);
      #pragma unroll
      for (int i=0;i<2;++i){
        int rowA = (wr << 5) + (i << 4) + lr;
        int bytA = ((rowA << 9) + (ka << 1)) ^ ((rowA & 7) << 4);
        af[i] = *(const bf16x8*)((const char*)Alds + bytA);
        int rowB = (wc << 5) + (i << 4) + lr;
        int bytB = ((rowB << 9) + (ka << 1)) ^ ((rowB & 7) << 4);
        bfr[i] = *(const bf16x8*)((const char*)Blds + bytB);
      }
      #pragma unroll
      for (int i=0;i<2;++i)
        #pragma unroll
        for (int j=0;j<2;++j)
          acc[i][j] = __builtin_amdgcn_mfma_f32_16x16x32_bf16(af[i], bfr[j], acc[i][j], 0, 0, 0);
    }

    #pragma unroll
    for (int i=0;i<2;++i){
      int mr0 = m0 + (wr << 5) + (i << 4) + (lg << 2);
      int rd[4];
      #pragma unroll
      for (int q=0;q<4;++q)
        rd[q] = (bb << 12) + idx[(mr0 + q) & 4095];   // inverse perm as scatter
      #pragma unroll
      for (int j=0;j<2;++j){
        int o = n0 + (wc << 5) + (j << 4) + lr;
        float bias = b_proj[o];
        #pragma unroll
        for (int q=0;q<4;++q)
          out[rd[q]*256 + o] = acc[i][j][q] + bias;
      }
    }
  }
}

// ---------------------------------------------------------------------------
extern "C" void kernel_launch(void* const* d_in, const int* in_sizes, int n_in,
                              void* d_out, int out_size, void* d_ws, size_t ws_size,
                              hipStream_t stream)
{
  const float* x      = (const float*)d_in[0];
  const int*   idx    = (const int*)  d_in[1];
  const float* w_qkv  = (const float*)d_in[2];
  const float* w_proj = (const float*)d_in[3];
  const float* b_proj = (const float*)d_in[4];
  float* out = (float*)d_out;

  char* ws = (char*)d_ws;
  unsigned short* Qb   = (unsigned short*)(ws);                  // 8 MiB
  unsigned short* KF   = (unsigned short*)(ws + (8u  << 20));    // 8 MiB (frag-major)
  unsigned short* VF   = (unsigned short*)(ws + (16u << 20));    // 8 MiB (frag-major)
  float*          operm= (float*)        (ws + (24u << 20));     // 16 MiB

  qkv_gemm<<<dim3(256, 2), 256, 0, stream>>>(x, idx, w_qkv, Qb, KF, VF);
  attn_kernel<<<dim3(1024), 256, 0, stream>>>(Qb, KF, VF, operm);
  proj_gemm<<<dim3(256, 2), 256, 0, stream>>>(operm, w_proj, b_proj, idx, out);
}